// Round 8
// baseline (46.493 us; speedup 1.0000x reference)
//
#include <hip/hip_runtime.h>
#include <hip/hip_bf16.h>
#include <math.h>

#define Bc 2
#define Cc 16
#define D4c 48
#define Kc 24
#define Hc 512
#define Wc 960
#define H4c 128
#define W4c 240
#define HW4 (H4c * W4c)   // 30720
#define S4 (Bc * HW4)     // 61440
#define HW1 (Hc * Wc)     // 491520
#define S1 (Bc * HW1)     // 983040
#define Gg 8              // disparity groups (lanes per pixel)
#define DPT 6             // disparities per thread
#define PPB 32            // pixels per block
#define HALO 47           // max disparity reach to the left
#define RW (PPB + HALO)   // 79: Rred halo row length

// ---------------------------------------------------------------------------
// Kernel B (fused): identical to R7.
// ---------------------------------------------------------------------------
__global__ __launch_bounds__(256, 6) void k_topk(const float* __restrict__ att,
                       const float* __restrict__ fl, const float* __restrict__ fr,
                       const float* __restrict__ wred,
                       float* __restrict__ oA4, float* __restrict__ oD4) {
    __shared__ float rrow[RW];   // Rred[pix0-47 .. pix0+31]
    __shared__ float lrow[PPB];  // Lred[pix0 .. pix0+31]

    const int tid   = threadIdx.x;
    const int wv    = tid >> 6;
    const int lane  = tid & 63;
    const int q     = lane >> 3;      // disparity group 0..7
    const int p     = lane & 7;       // pixel within wave
    const int plocal = wv * 8 + p;    // 0..31
    const int pix0  = blockIdx.x * PPB;
    const int pix   = pix0 + plocal;
    const int b     = pix0 / HW4;     // uniform per block (HW4 % 32 == 0)
    const int hw    = pix - b * HW4;
    const int col   = hw % W4c;
    const int dbase = q * DPT;

    // ---- att loads issued first (latency overlapped with feat stage) ----
    const float* ap = att + ((size_t)b * D4c + dbase) * HW4 + hw;
    float a[DPT];
#pragma unroll
    for (int i = 0; i < DPT; ++i) a[i] = ap[(size_t)i * HW4];

    // ---- feat channel-reduction into LDS (threads 0..110) ----
    {
        const int base = b * HW4;
        if (tid < RW) {
            int lin = pix0 - HALO + tid;
            if (lin < base) lin = base;            // clamped values never used
            const float* frb = fr + (size_t)b * Cc * HW4 + (lin - base);
            float acc = 0.f;
#pragma unroll
            for (int c = 0; c < Cc; ++c)
                acc = fmaf(wred[Cc + c], frb[(size_t)c * HW4], acc);
            rrow[tid] = acc;
        } else if (tid < RW + PPB) {
            int j = tid - RW;                      // 0..31
            const float* flb = fl + (size_t)b * Cc * HW4 + (pix0 + j - base);
            float acc = 0.f;
#pragma unroll
            for (int c = 0; c < Cc; ++c)
                acc = fmaf(wred[c], flb[(size_t)c * HW4], acc);
            lrow[j] = acc;
        }
    }
    __syncthreads();

    const float L = lrow[plocal];
    float RR[DPT];
#pragma unroll
    for (int i = 0; i < DPT; ++i) {
        int d = dbase + i;
        int idx = HALO + plocal - d;
        RR[i] = rrow[(col >= d) ? idx : HALO + plocal];   // masked at use
    }

    // ---- u32 monotone order keys ----
    unsigned u[DPT];
#pragma unroll
    for (int i = 0; i < DPT; ++i) {
        unsigned r = __float_as_uint(a[i]);
        u[i] = ((int)r < 0) ? ~r : (r | 0x80000000u);
    }

    // ---- global max (for stable exp) ----
    float m = a[0];
#pragma unroll
    for (int i = 1; i < DPT; ++i) m = fmaxf(m, a[i]);
    m = fmaxf(m, __shfl_xor(m, 8));
    m = fmaxf(m, __shfl_xor(m, 16));
    m = fmaxf(m, __shfl_xor(m, 32));

    // ---- beat counts ----
    int bc[DPT];
#pragma unroll
    for (int i = 0; i < DPT; ++i) bc[i] = 0;
#pragma unroll
    for (int i = 0; i < DPT; ++i) {
#pragma unroll
        for (int j = i + 1; j < DPT; ++j) {
            int c = (u[i] >= u[j]) ? 1 : 0;
            bc[j] += c;
            bc[i] += 1 - c;
        }
    }
#pragma unroll 2
    for (int c = 1; c < Gg; ++c) {
        const unsigned adj = ((q ^ c) < q) ? 1u : 0u;
        unsigned ui2[DPT], uj[DPT];
#pragma unroll
        for (int i = 0; i < DPT; ++i) ui2[i] = u[i] - adj;
#pragma unroll
        for (int j = 0; j < DPT; ++j) uj[j] = __shfl_xor(u[j], c << 3);
#pragma unroll
        for (int i = 0; i < DPT; ++i) {
#pragma unroll
            for (int j = 0; j < DPT; ++j) bc[i] += (uj[j] > ui2[i]) ? 1 : 0;
        }
    }

    // ---- per-thread partials: softmax sums, att regression, cost top-2 ----
    const float NEG = -3.0e38f;
    float s = 0.f, s2 = 0.f, n2 = 0.f;
    float v1 = NEG, v2 = NEG;
    int   i1 = 0,   i2v = 0;
#pragma unroll
    for (int i = 0; i < DPT; ++i) {
        const int d = dbase + i;
        float e = __expf(a[i] - m);
        s += e;
        bool sel = bc[i] < Kc;
        float es = sel ? e : 0.f;
        s2 += es;
        n2 = fmaf(es, (float)d, n2);
        float R = (col >= d) ? RR[i] : 0.f;
        float cst = sel ? e * (L + R) : NEG;
        bool g1 = cst > v1;
        bool g2 = cst > v2;
        float nv2 = g1 ? v1 : (g2 ? cst : v2);
        int   ni2 = g1 ? i1 : (g2 ? d : i2v);
        v1 = g1 ? cst : v1;
        i1 = g1 ? d : i1;
        v2 = nv2;
        i2v = ni2;
    }

    // ---- butterfly merge across the 8 groups (offsets 8,16,32) ----
#pragma unroll
    for (int st = 8; st <= 32; st <<= 1) {
        s  += __shfl_xor(s,  st);
        s2 += __shfl_xor(s2, st);
        n2 += __shfl_xor(n2, st);
        float ov1 = __shfl_xor(v1, st); int oi1 = __shfl_xor(i1,  st);
        float ov2 = __shfl_xor(v2, st); int oi2 = __shfl_xor(i2v, st);
        bool bt = (ov1 > v1) || (ov1 == v1 && oi1 < i1);
        float w1 = bt ? ov1 : v1;   int wi1 = bt ? oi1 : i1;
        float l1 = bt ? v1  : ov1;  int li1 = bt ? i1  : oi1;
        float w2 = bt ? ov2 : v2;   int wi2 = bt ? oi2 : i2v;
        bool b2 = (l1 > w2) || (l1 == w2 && li1 < wi2);
        v1 = w1; i1 = wi1;
        v2 = b2 ? l1 : w2;
        i2v = b2 ? li1 : wi2;
    }

    const float r = __expf((v2 - v1) / s);   // true cost delta = (v2-v1)/s
    if (q == 0) {
        oA4[pix] = n2 / s2;
        oD4[pix] = ((float)i1 + r * (float)i2v) / (1.f + r);
    }
}

// ---------------------------------------------------------------------------
// Kernel C: identical to R7.
// ---------------------------------------------------------------------------
__global__ __launch_bounds__(256) void k_upsample(const float* __restrict__ spx,
                           const float* __restrict__ A4, const float* __restrict__ D4p,
                           float* __restrict__ oA1, float* __restrict__ oD1) {
    int t = blockIdx.x * blockDim.x + threadIdx.x;
    if (t >= S1 / 4) return;
    const int Wq  = Wc / 4;              // 240
    int xg  = t % Wq;
    int rem = t / Wq;                    // b*Hc + y
    int y   = rem % Hc;
    int b   = rem / Hc;
    int yx0 = y * Wc + xg * 4;

    const float* sp = spx + (size_t)b * 9 * HW1 + yx0;
    float4 e[9];
    float4 ssum = {0.f, 0.f, 0.f, 0.f};
#pragma unroll
    for (int j = 0; j < 9; ++j) {
        float4 v = *(const float4*)(sp + (size_t)j * HW1);
        e[j].x = __expf(v.x); e[j].y = __expf(v.y);
        e[j].z = __expf(v.z); e[j].w = __expf(v.w);
        ssum.x += e[j].x; ssum.y += e[j].y; ssum.z += e[j].z; ssum.w += e[j].w;
    }

    const int y4 = y >> 2, x4 = xg;
    const float* A4b = A4 + b * HW4;
    const float* D4b = D4p + b * HW4;
    float4 accA = {0.f, 0.f, 0.f, 0.f}, accD = {0.f, 0.f, 0.f, 0.f};
#pragma unroll
    for (int dy = 0; dy < 3; ++dy) {
        int yy = y4 + dy - 1;
#pragma unroll
        for (int dx = 0; dx < 3; ++dx) {
            int xx = x4 + dx - 1;
            int j = dy * 3 + dx;
            bool ok = (yy >= 0 && yy < H4c && xx >= 0 && xx < W4c);
            int pI = ok ? (yy * W4c + xx) : 0;
            float ca = ok ? A4b[pI] : 0.f;
            float cd = ok ? D4b[pI] : 0.f;
            accA.x = fmaf(e[j].x, ca, accA.x); accA.y = fmaf(e[j].y, ca, accA.y);
            accA.z = fmaf(e[j].z, ca, accA.z); accA.w = fmaf(e[j].w, ca, accA.w);
            accD.x = fmaf(e[j].x, cd, accD.x); accD.y = fmaf(e[j].y, cd, accD.y);
            accD.z = fmaf(e[j].z, cd, accD.z); accD.w = fmaf(e[j].w, cd, accD.w);
        }
    }
    float4 inv;
    inv.x = 4.f * __builtin_amdgcn_rcpf(ssum.x);
    inv.y = 4.f * __builtin_amdgcn_rcpf(ssum.y);
    inv.z = 4.f * __builtin_amdgcn_rcpf(ssum.z);
    inv.w = 4.f * __builtin_amdgcn_rcpf(ssum.w);
    float4 oA, oD;
    oA.x = accA.x * inv.x; oA.y = accA.y * inv.y;
    oA.z = accA.z * inv.z; oA.w = accA.w * inv.w;
    oD.x = accD.x * inv.x; oD.y = accD.y * inv.y;
    oD.z = accD.z * inv.z; oD.w = accD.w * inv.w;
    *(float4*)(oA1 + (size_t)b * HW1 + yx0) = oA;
    *(float4*)(oD1 + (size_t)b * HW1 + yx0) = oD;
}

extern "C" void kernel_launch(void* const* d_in, const int* in_sizes, int n_in,
                              void* d_out, int out_size, void* d_ws, size_t ws_size,
                              hipStream_t stream) {
    const float* att  = (const float*)d_in[0];  // [B,1,48,128,240]
    const float* fl   = (const float*)d_in[1];  // [B,16,128,240]
    const float* fr   = (const float*)d_in[2];  // [B,16,128,240]
    const float* wred = (const float*)d_in[3];  // [32]
    const float* spx  = (const float*)d_in[4];  // [B,9,512,960]

    float* out = (float*)d_out;
    float* oA4 = out;                 // pred_att_x4 [B,128,240]
    float* oA1 = out + S4;            // pred_att_x1 [B,512,960]
    float* oD4 = out + S4 + S1;       // pred_x4     [B,128,240]
    float* oD1 = out + 2 * S4 + S1;   // pred_x1     [B,512,960]

    // ---- MEASUREMENT: duplicate k_topk launch writing to scratch.  Total
    // time delta vs R7 == k_topk duration (deterministic, outputs unaffected).
    if (ws_size >= (size_t)2 * S4 * sizeof(float)) {
        float* wA4 = (float*)d_ws;
        float* wD4 = wA4 + S4;
        k_topk<<<S4 / PPB, 256, 0, stream>>>(att, fl, fr, wred, wA4, wD4);
    }

    k_topk<<<S4 / PPB, 256, 0, stream>>>(att, fl, fr, wred, oA4, oD4);
    k_upsample<<<(S1 / 4 + 255) / 256, 256, 0, stream>>>(spx, oA4, oD4, oA1, oD1);
}

// Round 9
// 31.190 us; speedup vs baseline: 1.4907x; 1.4907x over previous
//
#include <hip/hip_runtime.h>
#include <hip/hip_bf16.h>
#include <math.h>

#define Bc 2
#define Cc 16
#define D4c 48
#define Kc 24
#define Hc 512
#define Wc 960
#define H4c 128
#define W4c 240
#define HW4 (H4c * W4c)   // 30720
#define S4 (Bc * HW4)     // 61440
#define HW1 (Hc * Wc)     // 491520
#define S1 (Bc * HW1)     // 983040
#define Gg 8              // disparity groups (lanes per pixel)
#define DPT 6             // disparities per thread
#define PPB 32            // pixels per block
#define HALO 47           // max disparity reach to the left
#define RW (PPB + HALO)   // 79: Rred halo row length

// ---------------------------------------------------------------------------
// VALU-only lane-xor helpers (DPP).  Group dim lives in lane bits [2:0], so
// xor 1..7 never crosses a 16-lane row:
//   xor1/2/3 : quad_perm (1 instr)
//   xor4     : row_shl:4 -> banks {0,2}  +  row_shr:4 -> banks {1,3}
// (GPUOpen cross-lane doc: row_shr:N => dst[i]=src[i-N], row_shl:N => src[i+N])
// ---------------------------------------------------------------------------
template<int CTRL, int BANK>
__device__ __forceinline__ int dpp_mov(int old_, int src) {
    return __builtin_amdgcn_update_dpp(old_, src, CTRL, 0xF, BANK, false);
}

template<int X>
__device__ __forceinline__ unsigned lxor_u(unsigned v) {
    int r = (int)v;
    if constexpr (X & 4) {
        int t = dpp_mov<0x104, 0x5>(r, r);   // row_shl:4 -> lanes {0-3,8-11} get src i+4
        r     = dpp_mov<0x114, 0xA>(t, r);   // row_shr:4 -> lanes {4-7,12-15} get src i-4
    }
    if constexpr ((X & 3) == 1) r = dpp_mov<0xB1, 0xF>(r, r);  // quad_perm [1,0,3,2]
    if constexpr ((X & 3) == 2) r = dpp_mov<0x4E, 0xF>(r, r);  // quad_perm [2,3,0,1]
    if constexpr ((X & 3) == 3) r = dpp_mov<0x1B, 0xF>(r, r);  // quad_perm [3,2,1,0]
    return (unsigned)r;
}
template<int X> __device__ __forceinline__ float lxor_f(float v) {
    return __uint_as_float(lxor_u<X>(__float_as_uint(v)));
}
template<int X> __device__ __forceinline__ int lxor_i(int v) {
    return (int)lxor_u<X>((unsigned)v);
}

// one cross-group rank round (partner group = q ^ C), all-VALU
template<int C>
__device__ __forceinline__ void rank_round(const unsigned (&u)[DPT], int (&bc)[DPT], int q) {
    const unsigned adj = ((q ^ C) < q) ? 1u : 0u;
    unsigned uj[DPT];
#pragma unroll
    for (int j = 0; j < DPT; ++j) uj[j] = lxor_u<C>(u[j]);
#pragma unroll
    for (int i = 0; i < DPT; ++i) {
        const unsigned ui2 = u[i] - adj;
#pragma unroll
        for (int j = 0; j < DPT; ++j) bc[i] += (uj[j] > ui2) ? 1 : 0;
    }
}

// one butterfly merge stage (sums + ordered top-2), all-VALU
template<int X>
__device__ __forceinline__ void merge_stage(float& s, float& s2, float& n2,
                                            float& v1, int& i1, float& v2, int& i2v) {
    s  += lxor_f<X>(s);
    s2 += lxor_f<X>(s2);
    n2 += lxor_f<X>(n2);
    float ov1 = lxor_f<X>(v1); int oi1 = lxor_i<X>(i1);
    float ov2 = lxor_f<X>(v2); int oi2 = lxor_i<X>(i2v);
    bool bt = (ov1 > v1) || (ov1 == v1 && oi1 < i1);
    float w1 = bt ? ov1 : v1;   int wi1 = bt ? oi1 : i1;
    float l1 = bt ? v1  : ov1;  int li1 = bt ? i1  : oi1;
    float w2 = bt ? ov2 : v2;   int wi2 = bt ? oi2 : i2v;
    bool b2 = (l1 > w2) || (l1 == w2 && li1 < wi2);
    v1 = w1; i1 = wi1;
    v2 = b2 ? l1 : w2;
    i2v = b2 ? li1 : wi2;
}

// ---------------------------------------------------------------------------
// Kernel B (fused): 8 lanes per pixel (q = lane&7), 8 pixels per wave.
// Feat channel-reduce -> LDS, then exact top-24 via all-pairs beat-count on
// u32 monotone keys; ALL cross-lane traffic on the VALU (DPP), no DS pipe.
// ---------------------------------------------------------------------------
__global__ __launch_bounds__(256, 6) void k_topk(const float* __restrict__ att,
                       const float* __restrict__ fl, const float* __restrict__ fr,
                       const float* __restrict__ wred,
                       float* __restrict__ oA4, float* __restrict__ oD4) {
    __shared__ float rrow[RW];   // Rred[pix0-47 .. pix0+31]
    __shared__ float lrow[PPB];  // Lred[pix0 .. pix0+31]

    const int tid    = threadIdx.x;
    const int wv     = tid >> 6;
    const int lane   = tid & 63;
    const int q      = lane & 7;      // disparity group 0..7  (low bits => DPP)
    const int p      = lane >> 3;     // pixel within wave 0..7
    const int plocal = wv * 8 + p;    // 0..31
    const int pix0   = blockIdx.x * PPB;
    const int pix    = pix0 + plocal;
    const int b      = pix0 / HW4;    // uniform per block (HW4 % 32 == 0)
    const int hw     = pix - b * HW4;
    const int col    = hw % W4c;
    const int dbase  = q * DPT;

    // ---- att loads issued first (latency overlapped with feat stage) ----
    const float* ap = att + ((size_t)b * D4c + dbase) * HW4 + hw;
    float a[DPT];
#pragma unroll
    for (int i = 0; i < DPT; ++i) a[i] = ap[(size_t)i * HW4];

    // ---- feat channel-reduction into LDS (threads 0..110) ----
    {
        const int base = b * HW4;
        if (tid < RW) {
            int lin = pix0 - HALO + tid;
            if (lin < base) lin = base;            // clamped values never used
            const float* frb = fr + (size_t)b * Cc * HW4 + (lin - base);
            float acc = 0.f;
#pragma unroll
            for (int c = 0; c < Cc; ++c)
                acc = fmaf(wred[Cc + c], frb[(size_t)c * HW4], acc);
            rrow[tid] = acc;
        } else if (tid < RW + PPB) {
            int j = tid - RW;                      // 0..31
            const float* flb = fl + (size_t)b * Cc * HW4 + (pix0 + j - base);
            float acc = 0.f;
#pragma unroll
            for (int c = 0; c < Cc; ++c)
                acc = fmaf(wred[c], flb[(size_t)c * HW4], acc);
            lrow[j] = acc;
        }
    }
    __syncthreads();

    const float L = lrow[plocal];
    float RR[DPT];
#pragma unroll
    for (int i = 0; i < DPT; ++i) {
        int d = dbase + i;
        int idx = HALO + plocal - d;
        RR[i] = rrow[(col >= d) ? idx : HALO + plocal];   // masked at use
    }

    // ---- u32 monotone order keys ----
    unsigned u[DPT];
#pragma unroll
    for (int i = 0; i < DPT; ++i) {
        unsigned r = __float_as_uint(a[i]);
        u[i] = ((int)r < 0) ? ~r : (r | 0x80000000u);
    }

    // ---- global max over all 48 (butterfly on DPP) ----
    float m = a[0];
#pragma unroll
    for (int i = 1; i < DPT; ++i) m = fmaxf(m, a[i]);
    m = fmaxf(m, lxor_f<1>(m));
    m = fmaxf(m, lxor_f<2>(m));
    m = fmaxf(m, lxor_f<4>(m));

    // ---- beat counts ----
    int bc[DPT];
#pragma unroll
    for (int i = 0; i < DPT; ++i) bc[i] = 0;
    // own group: pair (i<j): i beats j iff u[i] >= u[j] (index tiebreak)
#pragma unroll
    for (int i = 0; i < DPT; ++i) {
#pragma unroll
        for (int j = i + 1; j < DPT; ++j) {
            int c = (u[i] >= u[j]) ? 1 : 0;
            bc[j] += c;
            bc[i] += 1 - c;
        }
    }
    // cross groups, all-VALU
    rank_round<1>(u, bc, q);
    rank_round<2>(u, bc, q);
    rank_round<3>(u, bc, q);
    rank_round<4>(u, bc, q);
    rank_round<5>(u, bc, q);
    rank_round<6>(u, bc, q);
    rank_round<7>(u, bc, q);

    // ---- per-thread partials: softmax sums, att regression, cost top-2 ----
    const float NEG = -3.0e38f;
    float s = 0.f, s2 = 0.f, n2 = 0.f;
    float v1 = NEG, v2 = NEG;
    int   i1 = 0,   i2v = 0;
#pragma unroll
    for (int i = 0; i < DPT; ++i) {
        const int d = dbase + i;
        float e = __expf(a[i] - m);
        s += e;
        bool sel = bc[i] < Kc;
        float es = sel ? e : 0.f;
        s2 += es;
        n2 = fmaf(es, (float)d, n2);
        float R = (col >= d) ? RR[i] : 0.f;
        float cst = sel ? e * (L + R) : NEG;
        bool g1 = cst > v1;
        bool g2 = cst > v2;
        float nv2 = g1 ? v1 : (g2 ? cst : v2);
        int   ni2 = g1 ? i1 : (g2 ? d : i2v);
        v1 = g1 ? cst : v1;
        i1 = g1 ? d : i1;
        v2 = nv2;
        i2v = ni2;
    }

    // ---- butterfly merge across the 8 groups (xor 1,2,4 on DPP) ----
    merge_stage<1>(s, s2, n2, v1, i1, v2, i2v);
    merge_stage<2>(s, s2, n2, v1, i1, v2, i2v);
    merge_stage<4>(s, s2, n2, v1, i1, v2, i2v);

    const float r = __expf((v2 - v1) / s);   // true cost delta = (v2-v1)/s
    if (q == 0) {
        oA4[pix] = n2 / s2;
        oD4[pix] = ((float)i1 + r * (float)i2v) / (1.f + r);
    }
}

// ---------------------------------------------------------------------------
// Kernel C: superpixel-guided 4x upsample; one thread = 4 consecutive x
// (they share one coarse 3x3 neighborhood).  No max-sub (logits ~N(0,1)).
// ---------------------------------------------------------------------------
__global__ __launch_bounds__(256) void k_upsample(const float* __restrict__ spx,
                           const float* __restrict__ A4, const float* __restrict__ D4p,
                           float* __restrict__ oA1, float* __restrict__ oD1) {
    int t = blockIdx.x * blockDim.x + threadIdx.x;
    if (t >= S1 / 4) return;
    const int Wq  = Wc / 4;              // 240
    int xg  = t % Wq;
    int rem = t / Wq;                    // b*Hc + y
    int y   = rem % Hc;
    int b   = rem / Hc;
    int yx0 = y * Wc + xg * 4;

    const float* sp = spx + (size_t)b * 9 * HW1 + yx0;
    float4 e[9];
    float4 ssum = {0.f, 0.f, 0.f, 0.f};
#pragma unroll
    for (int j = 0; j < 9; ++j) {
        float4 v = *(const float4*)(sp + (size_t)j * HW1);
        e[j].x = __expf(v.x); e[j].y = __expf(v.y);
        e[j].z = __expf(v.z); e[j].w = __expf(v.w);
        ssum.x += e[j].x; ssum.y += e[j].y; ssum.z += e[j].z; ssum.w += e[j].w;
    }

    const int y4 = y >> 2, x4 = xg;
    const float* A4b = A4 + b * HW4;
    const float* D4b = D4p + b * HW4;
    float4 accA = {0.f, 0.f, 0.f, 0.f}, accD = {0.f, 0.f, 0.f, 0.f};
#pragma unroll
    for (int dy = 0; dy < 3; ++dy) {
        int yy = y4 + dy - 1;
#pragma unroll
        for (int dx = 0; dx < 3; ++dx) {
            int xx = x4 + dx - 1;
            int j = dy * 3 + dx;
            bool ok = (yy >= 0 && yy < H4c && xx >= 0 && xx < W4c);
            int pI = ok ? (yy * W4c + xx) : 0;
            float ca = ok ? A4b[pI] : 0.f;
            float cd = ok ? D4b[pI] : 0.f;
            accA.x = fmaf(e[j].x, ca, accA.x); accA.y = fmaf(e[j].y, ca, accA.y);
            accA.z = fmaf(e[j].z, ca, accA.z); accA.w = fmaf(e[j].w, ca, accA.w);
            accD.x = fmaf(e[j].x, cd, accD.x); accD.y = fmaf(e[j].y, cd, accD.y);
            accD.z = fmaf(e[j].z, cd, accD.z); accD.w = fmaf(e[j].w, cd, accD.w);
        }
    }
    float4 inv;
    inv.x = 4.f * __builtin_amdgcn_rcpf(ssum.x);
    inv.y = 4.f * __builtin_amdgcn_rcpf(ssum.y);
    inv.z = 4.f * __builtin_amdgcn_rcpf(ssum.z);
    inv.w = 4.f * __builtin_amdgcn_rcpf(ssum.w);
    float4 oA, oD;
    oA.x = accA.x * inv.x; oA.y = accA.y * inv.y;
    oA.z = accA.z * inv.z; oA.w = accA.w * inv.w;
    oD.x = accD.x * inv.x; oD.y = accD.y * inv.y;
    oD.z = accD.z * inv.z; oD.w = accD.w * inv.w;
    *(float4*)(oA1 + (size_t)b * HW1 + yx0) = oA;
    *(float4*)(oD1 + (size_t)b * HW1 + yx0) = oD;
}

extern "C" void kernel_launch(void* const* d_in, const int* in_sizes, int n_in,
                              void* d_out, int out_size, void* d_ws, size_t ws_size,
                              hipStream_t stream) {
    const float* att  = (const float*)d_in[0];  // [B,1,48,128,240]
    const float* fl   = (const float*)d_in[1];  // [B,16,128,240]
    const float* fr   = (const float*)d_in[2];  // [B,16,128,240]
    const float* wred = (const float*)d_in[3];  // [32]
    const float* spx  = (const float*)d_in[4];  // [B,9,512,960]

    float* out = (float*)d_out;
    float* oA4 = out;                 // pred_att_x4 [B,128,240]
    float* oA1 = out + S4;            // pred_att_x1 [B,512,960]
    float* oD4 = out + S4 + S1;       // pred_x4     [B,128,240]
    float* oD1 = out + 2 * S4 + S1;   // pred_x1     [B,512,960]

    k_topk<<<S4 / PPB, 256, 0, stream>>>(att, fl, fr, wred, oA4, oD4);
    k_upsample<<<(S1 / 4 + 255) / 256, 256, 0, stream>>>(spx, oA4, oD4, oA1, oD1);
}